// Round 9
// baseline (1563.759 us; speedup 1.0000x reference)
//
#include <hip/hip_runtime.h>
#include <math.h>

#define B_ 512
#define T_ 24
#define TM1 23
#define D_ 1024
#define OUT_ 325
#define HORIZON_ 12

typedef unsigned short ushort_t;
typedef __attribute__((ext_vector_type(8))) short bf16x8;
typedef __attribute__((ext_vector_type(4))) float f32x4;

#define MFMA16(a, b, c) __builtin_amdgcn_mfma_f32_16x16x32_bf16((a), (b), (c), 0, 0, 0)

__device__ __forceinline__ ushort_t f2b(float f) {
  union { float f; unsigned u; } v; v.f = f;
  unsigned r = (v.u + 0x7fffu + ((v.u >> 16) & 1u)) >> 16;
  return (ushort_t)r;
}
__device__ __forceinline__ float b2f(ushort_t s) {
  union { unsigned u; float f; } v; v.u = ((unsigned)s) << 16;
  return v.f;
}

// 16-row-granular packed fragment layout for (M x K) bf16, M%16==0, K%32==0.
// Segment (m>>4, k>>5) = 512 contiguous elems; lane l holds 16B of it.
__device__ __forceinline__ size_t pidx16(int m, int k, int K) {
  return (((size_t)(m >> 4) * (K >> 5) + (k >> 5)) * 64
          + ((m & 15) + (((k >> 3) & 3) << 4))) * 8 + (k & 7);
}

#define GLOAD16(src, dst) \
  __builtin_amdgcn_global_load_lds((const __attribute__((address_space(1))) void*)(src), \
                                   (__attribute__((address_space(3))) void*)(dst), 16, 0, 0)

__device__ __forceinline__ bf16x8 ldfrag(const ushort_t* p) {
  return *(const bf16x8*)p;
}

// =============== diagonal encoder step: direct-register MFMA, no LDS/barriers =======
// 1024 blocks: z = bid>>9, bx = (bid>>5)&15, by = bid&31 (bid%8=by%8 -> XCD affinity)
// z=0: layer-0 gh-only cell at t=k; z=1: layer-1 FULL cell at t=k-1.
__global__ __launch_bounds__(256) void enc_diag(
    int k,
    const ushort_t* __restrict__ Hp0, const float* __restrict__ Hf0,
    float* __restrict__ Hf0o, ushort_t* __restrict__ Hp0o,
    const ushort_t* __restrict__ Whh0, const float* __restrict__ bhh0,
    const ushort_t* __restrict__ GXbuf, ushort_t* __restrict__ Y0p,
    const ushort_t* __restrict__ Hp1, const float* __restrict__ Hf1,
    float* __restrict__ Hf1o, ushort_t* __restrict__ Hp1o,
    const ushort_t* __restrict__ Wih1, const ushort_t* __restrict__ Whh1,
    const float* __restrict__ bih1, const float* __restrict__ bhh1)
{
  const int tid = threadIdx.x, lane = tid & 63, w = tid >> 6;
  const int bid = blockIdx.x;
  const int z = bid >> 9, bx = (bid >> 5) & 15, by = bid & 31;
  const int wm = w >> 1, wn = w & 1;
  const int d = by * 32 + wn * 16 + (lane & 15);
  const int lo = lane * 8;

  if (z == 0) {
    if (k >= TM1) return;
    const ushort_t* GXslot = GXbuf + (size_t)k * 512 * 3072;
    ushort_t* Seqp = Y0p + (size_t)k * 512 * 1024;
    f32x4 acc[3] = {};
    const ushort_t* aP = Hp0 + ((size_t)(bx * 2 + wm) * 32) * 512 + lo;
    const ushort_t* bP0 = Whh0 + ((size_t)(0 * 64 + by * 2 + wn) * 32) * 512 + lo;
    const ushort_t* bP1 = Whh0 + ((size_t)(1 * 64 + by * 2 + wn) * 32) * 512 + lo;
    const ushort_t* bP2 = Whh0 + ((size_t)(2 * 64 + by * 2 + wn) * 32) * 512 + lo;
    #pragma unroll 4
    for (int kb = 0; kb < 32; ++kb) {
      bf16x8 a  = ldfrag(aP  + kb * 512);
      bf16x8 b0 = ldfrag(bP0 + kb * 512);
      bf16x8 b1 = ldfrag(bP1 + kb * 512);
      bf16x8 b2 = ldfrag(bP2 + kb * 512);
      acc[0] = MFMA16(a, b0, acc[0]);
      acc[1] = MFMA16(a, b1, acc[1]);
      acc[2] = MFMA16(a, b2, acc[2]);
    }
    const float bh_r = bhh0[d], bh_z = bhh0[D_ + d], bh_n = bhh0[2 * D_ + d];
    #pragma unroll
    for (int q = 0; q < 4; ++q) {
      int m = bx * 32 + wm * 16 + ((lane >> 4) << 2) + q;
      const ushort_t* gxp = GXslot + (size_t)m * 3072 + d;
      float gx_r = b2f(gxp[0]), gx_z = b2f(gxp[D_]), gx_n = b2f(gxp[2 * D_]);
      float rr = 1.f / (1.f + __expf(-(gx_r + acc[0][q] + bh_r)));
      float zz = 1.f / (1.f + __expf(-(gx_z + acc[1][q] + bh_z)));
      float nn = tanhf(gx_n + rr * (acc[2][q] + bh_n));
      float h = Hf0[(size_t)m * D_ + d];
      float hnew = (1.f - zz) * nn + zz * h;
      Hf0o[(size_t)m * D_ + d] = hnew;
      ushort_t hb = f2b(hnew);
      size_t pi = pidx16(m, d, D_);
      Hp0o[pi] = hb; Seqp[pi] = hb;
    }
  } else {
    if (k < 1) return;
    const ushort_t* Xp_ = Y0p + (size_t)(k - 1) * 512 * 1024;
    f32x4 accx[3] = {}, acch[3] = {};
    const ushort_t* axP = Xp_ + ((size_t)(bx * 2 + wm) * 32) * 512 + lo;
    const ushort_t* ahP = Hp1 + ((size_t)(bx * 2 + wm) * 32) * 512 + lo;
    const ushort_t* bxP0 = Wih1 + ((size_t)(0 * 64 + by * 2 + wn) * 32) * 512 + lo;
    const ushort_t* bxP1 = Wih1 + ((size_t)(1 * 64 + by * 2 + wn) * 32) * 512 + lo;
    const ushort_t* bxP2 = Wih1 + ((size_t)(2 * 64 + by * 2 + wn) * 32) * 512 + lo;
    const ushort_t* bhP0 = Whh1 + ((size_t)(0 * 64 + by * 2 + wn) * 32) * 512 + lo;
    const ushort_t* bhP1 = Whh1 + ((size_t)(1 * 64 + by * 2 + wn) * 32) * 512 + lo;
    const ushort_t* bhP2 = Whh1 + ((size_t)(2 * 64 + by * 2 + wn) * 32) * 512 + lo;
    #pragma unroll 2
    for (int kb = 0; kb < 32; ++kb) {
      bf16x8 ax = ldfrag(axP + kb * 512);
      bf16x8 ah = ldfrag(ahP + kb * 512);
      bf16x8 x0 = ldfrag(bxP0 + kb * 512);
      bf16x8 x1 = ldfrag(bxP1 + kb * 512);
      bf16x8 x2 = ldfrag(bxP2 + kb * 512);
      bf16x8 h0 = ldfrag(bhP0 + kb * 512);
      bf16x8 h1 = ldfrag(bhP1 + kb * 512);
      bf16x8 h2 = ldfrag(bhP2 + kb * 512);
      accx[0] = MFMA16(ax, x0, accx[0]);
      acch[0] = MFMA16(ah, h0, acch[0]);
      accx[1] = MFMA16(ax, x1, accx[1]);
      acch[1] = MFMA16(ah, h1, acch[1]);
      accx[2] = MFMA16(ax, x2, accx[2]);
      acch[2] = MFMA16(ah, h2, acch[2]);
    }
    const float bi_r = bih1[d], bi_z = bih1[D_ + d], bi_n = bih1[2 * D_ + d];
    const float bh_r = bhh1[d], bh_z = bhh1[D_ + d], bh_n = bhh1[2 * D_ + d];
    #pragma unroll
    for (int q = 0; q < 4; ++q) {
      int m = bx * 32 + wm * 16 + ((lane >> 4) << 2) + q;
      float rr = 1.f / (1.f + __expf(-(accx[0][q] + bi_r + acch[0][q] + bh_r)));
      float zz = 1.f / (1.f + __expf(-(accx[1][q] + bi_z + acch[1][q] + bh_z)));
      float nn = tanhf(accx[2][q] + bi_n + rr * (acch[2][q] + bh_n));
      float h = Hf1[(size_t)m * D_ + d];
      float hnew = (1.f - zz) * nn + zz * h;
      Hf1o[(size_t)m * D_ + d] = hnew;
      Hp1o[pidx16(m, d, D_)] = f2b(hnew);
    }
  }
}

// =============== decoder layer-0 cell: direct-register, gh (K=1024) + gx0 (K=352) ===
__global__ __launch_bounds__(256) void dec_cell0(
    const ushort_t* __restrict__ DCp, const ushort_t* __restrict__ Hp,
    const float* __restrict__ Hf,
    const ushort_t* __restrict__ W0dp, const ushort_t* __restrict__ Whh0,
    const float* __restrict__ bhh0,
    const float* __restrict__ CTt, const float* __restrict__ CBd,
    const int* __restrict__ timev, int step,
    float* __restrict__ Hf_out, ushort_t* __restrict__ Hp_out)
{
  const int tid = threadIdx.x, lane = tid & 63, w = tid >> 6;
  const int bid = blockIdx.x;
  const int bx = bid >> 5, by = bid & 31;
  const int wm = w >> 1, wn = w & 1;
  const int d = by * 32 + wn * 16 + (lane & 15);
  const int lo = lane * 8;
  f32x4 accx[3] = {}, acch[3] = {};

  {
    const ushort_t* aP = Hp + ((size_t)(bx * 2 + wm) * 32) * 512 + lo;
    const ushort_t* bP0 = Whh0 + ((size_t)(0 * 64 + by * 2 + wn) * 32) * 512 + lo;
    const ushort_t* bP1 = Whh0 + ((size_t)(1 * 64 + by * 2 + wn) * 32) * 512 + lo;
    const ushort_t* bP2 = Whh0 + ((size_t)(2 * 64 + by * 2 + wn) * 32) * 512 + lo;
    #pragma unroll 4
    for (int kb = 0; kb < 32; ++kb) {
      bf16x8 a  = ldfrag(aP  + kb * 512);
      bf16x8 b0 = ldfrag(bP0 + kb * 512);
      bf16x8 b1 = ldfrag(bP1 + kb * 512);
      bf16x8 b2 = ldfrag(bP2 + kb * 512);
      acch[0] = MFMA16(a, b0, acch[0]);
      acch[1] = MFMA16(a, b1, acch[1]);
      acch[2] = MFMA16(a, b2, acch[2]);
    }
  }
  {
    const ushort_t* aP = DCp + ((size_t)(bx * 2 + wm) * 11) * 512 + lo;
    const ushort_t* bP0 = W0dp + ((size_t)(0 * 64 + by * 2 + wn) * 11) * 512 + lo;
    const ushort_t* bP1 = W0dp + ((size_t)(1 * 64 + by * 2 + wn) * 11) * 512 + lo;
    const ushort_t* bP2 = W0dp + ((size_t)(2 * 64 + by * 2 + wn) * 11) * 512 + lo;
    #pragma unroll
    for (int kb = 0; kb < 11; ++kb) {
      bf16x8 a  = ldfrag(aP  + kb * 512);
      bf16x8 b0 = ldfrag(bP0 + kb * 512);
      bf16x8 b1 = ldfrag(bP1 + kb * 512);
      bf16x8 b2 = ldfrag(bP2 + kb * 512);
      accx[0] = MFMA16(a, b0, accx[0]);
      accx[1] = MFMA16(a, b1, accx[1]);
      accx[2] = MFMA16(a, b2, accx[2]);
    }
  }

  const float bh_r = bhh0[d], bh_z = bhh0[D_ + d], bh_n = bhh0[2 * D_ + d];
  #pragma unroll
  for (int q = 0; q < 4; ++q) {
    int m = bx * 32 + wm * 16 + ((lane >> 4) << 2) + q;
    int ti = (timev[m * T_ + (T_ - 1)] + step) % 288;
    const float* ctt = CTt + (size_t)ti * 3072;
    const float* cb  = CBd + (size_t)m * 3072;
    float gx_r = accx[0][q] + ctt[d] + cb[d];
    float gx_z = accx[1][q] + ctt[D_ + d] + cb[D_ + d];
    float gx_n = accx[2][q] + ctt[2 * D_ + d] + cb[2 * D_ + d];
    float rr = 1.f / (1.f + __expf(-(gx_r + acch[0][q] + bh_r)));
    float zz = 1.f / (1.f + __expf(-(gx_z + acch[1][q] + bh_z)));
    float nn = tanhf(gx_n + rr * (acch[2][q] + bh_n));
    float h = Hf[(size_t)m * D_ + d];
    float hnew = (1.f - zz) * nn + zz * h;
    Hf_out[(size_t)m * D_ + d] = hnew;
    Hp_out[pidx16(m, d, D_)] = f2b(hnew);
  }
}

// =============== decoder layer-1 full cell: direct-register ===============
__global__ __launch_bounds__(256) void gru_cell32(
    const ushort_t* __restrict__ Xp_, const ushort_t* __restrict__ Hp,
    const float* __restrict__ Hf,
    const ushort_t* __restrict__ Wih_l, const ushort_t* __restrict__ Whh_l,
    const float* __restrict__ bih_l, const float* __restrict__ bhh_l,
    float* __restrict__ Hf_out, ushort_t* __restrict__ Hp_out)
{
  const int tid = threadIdx.x, lane = tid & 63, w = tid >> 6;
  const int bid = blockIdx.x;
  const int bx = bid >> 5, by = bid & 31;
  const int wm = w >> 1, wn = w & 1;
  const int d = by * 32 + wn * 16 + (lane & 15);
  const int lo = lane * 8;
  f32x4 accx[3] = {}, acch[3] = {};

  const ushort_t* axP = Xp_ + ((size_t)(bx * 2 + wm) * 32) * 512 + lo;
  const ushort_t* ahP = Hp  + ((size_t)(bx * 2 + wm) * 32) * 512 + lo;
  const ushort_t* bxP0 = Wih_l + ((size_t)(0 * 64 + by * 2 + wn) * 32) * 512 + lo;
  const ushort_t* bxP1 = Wih_l + ((size_t)(1 * 64 + by * 2 + wn) * 32) * 512 + lo;
  const ushort_t* bxP2 = Wih_l + ((size_t)(2 * 64 + by * 2 + wn) * 32) * 512 + lo;
  const ushort_t* bhP0 = Whh_l + ((size_t)(0 * 64 + by * 2 + wn) * 32) * 512 + lo;
  const ushort_t* bhP1 = Whh_l + ((size_t)(1 * 64 + by * 2 + wn) * 32) * 512 + lo;
  const ushort_t* bhP2 = Whh_l + ((size_t)(2 * 64 + by * 2 + wn) * 32) * 512 + lo;
  #pragma unroll 2
  for (int kb = 0; kb < 32; ++kb) {
    bf16x8 ax = ldfrag(axP + kb * 512);
    bf16x8 ah = ldfrag(ahP + kb * 512);
    bf16x8 x0 = ldfrag(bxP0 + kb * 512);
    bf16x8 x1 = ldfrag(bxP1 + kb * 512);
    bf16x8 x2 = ldfrag(bxP2 + kb * 512);
    bf16x8 h0 = ldfrag(bhP0 + kb * 512);
    bf16x8 h1 = ldfrag(bhP1 + kb * 512);
    bf16x8 h2 = ldfrag(bhP2 + kb * 512);
    accx[0] = MFMA16(ax, x0, accx[0]);
    acch[0] = MFMA16(ah, h0, acch[0]);
    accx[1] = MFMA16(ax, x1, accx[1]);
    acch[1] = MFMA16(ah, h1, acch[1]);
    accx[2] = MFMA16(ax, x2, accx[2]);
    acch[2] = MFMA16(ah, h2, acch[2]);
  }

  const float bi_r = bih_l[d], bi_z = bih_l[D_ + d], bi_n = bih_l[2 * D_ + d];
  const float bh_r = bhh_l[d], bh_z = bhh_l[D_ + d], bh_n = bhh_l[2 * D_ + d];
  #pragma unroll
  for (int q = 0; q < 4; ++q) {
    int m = bx * 32 + wm * 16 + ((lane >> 4) << 2) + q;
    float rr = 1.f / (1.f + __expf(-(accx[0][q] + bi_r + acch[0][q] + bh_r)));
    float zz = 1.f / (1.f + __expf(-(accx[1][q] + bi_z + acch[1][q] + bh_z)));
    float nn = tanhf(accx[2][q] + bi_n + rr * (acch[2][q] + bh_n));
    float h = Hf[(size_t)m * D_ + d];
    float hnew = (1.f - zz) * nn + zz * h;
    Hf_out[(size_t)m * D_ + d] = hnew;
    Hp_out[pidx16(m, d, D_)] = f2b(hnew);
  }
}

// =============== encoder layer-0 gx: 128-tile, K=352, padded LDS-transpose epilogue ==
__global__ __launch_bounds__(256) void gemm_gx0_enc(
    const ushort_t* __restrict__ Ap, const ushort_t* __restrict__ W0p,
    const float* __restrict__ CTt, const float* __restrict__ CBe,
    const int* __restrict__ timev,
    ushort_t* __restrict__ GX)
{
  __shared__ ushort_t lds[2][16 * 512];
  const int tid = threadIdx.x, lane = tid & 63, w = tid >> 6;
  const int bx = blockIdx.x, by = blockIdx.y;
  const int wm = w >> 1, wn = w & 1;
  f32x4 acc[4][4] = {};

  auto stage = [&](int buf, int kb) {
    #pragma unroll
    for (int r = 0; r < 4; ++r) {
      int s = r * 4 + w;
      const ushort_t* src = (s < 8)
          ? Ap  + ((size_t)((bx * 8 + s) * 11 + kb)) * 512 + lane * 8
          : W0p + ((size_t)((by * 8 + (s - 8)) * 11 + kb)) * 512 + lane * 8;
      GLOAD16(src, &lds[buf][s * 512 + lane * 8]);
    }
  };

  stage(0, 0); __syncthreads();
  int cur = 0;
  for (int kb = 0; kb < 11; ++kb) {
    if (kb + 1 < 11) stage(cur ^ 1, kb + 1);
    const ushort_t* L = lds[cur];
    bf16x8 af[4], bf[4];
    #pragma unroll
    for (int f = 0; f < 4; ++f) {
      af[f] = *(const bf16x8*)(L + (wm * 4 + f) * 512 + lane * 8);
      bf[f] = *(const bf16x8*)(L + (8 + wn * 4 + f) * 512 + lane * 8);
    }
    #pragma unroll
    for (int fm = 0; fm < 4; ++fm)
      #pragma unroll
      for (int fn = 0; fn < 4; ++fn)
        acc[fm][fn] = MFMA16(af[fm], bf[fn], acc[fm][fn]);
    __syncthreads(); cur ^= 1;
  }

  // epilogue: per-fm LDS transpose (row stride 132 f32 to avoid bank aliasing)
  float* fl = (float*)&lds[0][0]; // [32][132] f32 = 16.9 KB
  for (int fm = 0; fm < 4; ++fm) {
    #pragma unroll
    for (int q = 0; q < 4; ++q)
      #pragma unroll
      for (int fn = 0; fn < 4; ++fn)
        fl[(wm * 16 + ((lane >> 4) << 2) + q) * 132 + wn * 64 + fn * 16 + (lane & 15)]
            = acc[fm][fn][q];
    __syncthreads();
    #pragma unroll
    for (int it = 0; it < 2; ++it) {
      int idx = it * 256 + tid;
      int ml = idx >> 4, n0 = (idx & 15) * 8;
      int m = bx * 128 + (ml >> 4) * 64 + fm * 16 + (ml & 15);
      int b = m / 23, t = m - b * 23;
      int ti = timev[b * T_ + t] % 288;
      const float* ctt = CTt + (size_t)ti * 3072 + by * 128 + n0;
      const float* cb  = CBe + (size_t)b * 3072 + by * 128 + n0;
      const float* fr  = fl + ml * 132 + n0;
      bf16x8 o;
      #pragma unroll
      for (int j = 0; j < 8; ++j) o[j] = f2b(fr[j] + ctt[j] + cb[j]);
      *(bf16x8*)(GX + ((size_t)t * 512 + b) * 3072 + by * 128 + n0) = o;
    }
    __syncthreads();
  }
}

// =============== generic 64-tile GEMM with epilogues ===============
template<int EPI>
__global__ __launch_bounds__(256) void gemm64(
    const ushort_t* __restrict__ Ap, const ushort_t* __restrict__ Wp, int K32,
    const float* __restrict__ bias, int step,
    ushort_t* __restrict__ outp, float* __restrict__ outf,
    float* __restrict__ dout, ushort_t* __restrict__ DCp)
{
  __shared__ ushort_t lds[2][8 * 512];
  const int tid = threadIdx.x, lane = tid & 63, w = tid >> 6;
  const int bx = blockIdx.x, by = blockIdx.y;
  const int wm = w >> 1, wn = w & 1;
  f32x4 acc[2][2] = {};

  auto stage = [&](int buf, int kb) {
    #pragma unroll
    for (int r = 0; r < 2; ++r) {
      int s = r * 4 + w;
      const ushort_t* src = (s < 4)
          ? Ap + ((size_t)((bx * 4 + s) * K32 + kb)) * 512 + lane * 8
          : Wp + ((size_t)((by * 4 + (s - 4)) * K32 + kb)) * 512 + lane * 8;
      GLOAD16(src, &lds[buf][s * 512 + lane * 8]);
    }
  };

  stage(0, 0); __syncthreads();
  int cur = 0;
  for (int kb = 0; kb < K32; ++kb) {
    if (kb + 1 < K32) stage(cur ^ 1, kb + 1);
    const ushort_t* L = lds[cur];
    bf16x8 af[2], bf[2];
    #pragma unroll
    for (int f = 0; f < 2; ++f) {
      af[f] = *(const bf16x8*)(L + (wm * 2 + f) * 512 + lane * 8);
      bf[f] = *(const bf16x8*)(L + (4 + wn * 2 + f) * 512 + lane * 8);
    }
    #pragma unroll
    for (int fm = 0; fm < 2; ++fm)
      #pragma unroll
      for (int fn = 0; fn < 2; ++fn)
        acc[fm][fn] = MFMA16(af[fm], bf[fn], acc[fm][fn]);
    __syncthreads(); cur ^= 1;
  }

  #pragma unroll
  for (int fm = 0; fm < 2; ++fm) {
    #pragma unroll
    for (int q = 0; q < 4; ++q) {
      int m = bx * 64 + wm * 32 + fm * 16 + ((lane >> 4) << 2) + q;
      #pragma unroll
      for (int fn = 0; fn < 2; ++fn) {
        int n = by * 64 + wn * 32 + fn * 16 + (lane & 15);
        float v = acc[fm][fn][q];
        if (EPI == 0) {
          if (n < 352) outp[pidx16(m, n, 352)] = f2b(v);
        } else if (EPI == 1) {
          outf[(size_t)m * 3072 + n] = v;
        } else {
          if (n < OUT_) {
            v += bias[n] + outf[(size_t)m * OUT_ + n];
            dout[((size_t)m * HORIZON_ + step) * OUT_ + n] = v;
            outf[(size_t)m * OUT_ + n] = v;
            DCp[pidx16(m, n, 352)] = f2b(v);
          }
        }
      }
    }
  }
}

// =============== CB = day' + b_data' + bih (per batch row) ===============
__global__ void build_cb(const float* __restrict__ CT, const float* __restrict__ bih0,
                         const int* __restrict__ weekday, float* __restrict__ CB)
{
  int idx = blockIdx.x * 256 + threadIdx.x;
  if (idx >= 512 * 3072) return;
  int b = idx / 3072, n = idx - b * 3072;
  CB[idx] = CT[(size_t)(288 + weekday[b]) * 3072 + n] + CT[(size_t)295 * 3072 + n] + bih0[n];
}

// ================= dest-major pack kernels =================
__global__ void pack_k1024(const float* __restrict__ src, ushort_t* __restrict__ dst,
                           int total, int Mvalid) {
  int stride = gridDim.x * 256;
  for (int i = blockIdx.x * 256 + threadIdx.x; i < total; i += stride) {
    int seg = i >> 6, q = i & 63;
    int m = (seg >> 5) * 16 + (q & 15);
    int k = (seg & 31) * 32 + (q >> 4) * 8;
    bf16x8 o;
    if (m < Mvalid) {
      const float* s = src + (size_t)m * 1024 + k;
      float4 v0 = *(const float4*)s, v1 = *(const float4*)(s + 4);
      o[0] = f2b(v0.x); o[1] = f2b(v0.y); o[2] = f2b(v0.z); o[3] = f2b(v0.w);
      o[4] = f2b(v1.x); o[5] = f2b(v1.y); o[6] = f2b(v1.z); o[7] = f2b(v1.w);
    } else o = bf16x8{0,0,0,0,0,0,0,0};
    *(bf16x8*)(dst + (size_t)i * 8) = o;
  }
}
__global__ void pack_wm(const float* __restrict__ w_mlp, ushort_t* __restrict__ dst) {
  int stride = gridDim.x * 256;
  for (int i = blockIdx.x * 256 + threadIdx.x; i < 384 * 128; i += stride) {
    int seg = i >> 6, q = i & 63;
    int n = (seg >> 5) * 16 + (q & 15);
    int k = (seg & 31) * 32 + (q >> 4) * 8;
    bf16x8 o;
    #pragma unroll
    for (int j = 0; j < 8; ++j)
      o[j] = (n < OUT_) ? f2b(w_mlp[(size_t)(k + j) * OUT_ + n]) : (short)0;
    *(bf16x8*)(dst + (size_t)i * 8) = o;
  }
}
__global__ void pack_ct(const float* __restrict__ time_table, const float* __restrict__ day_table,
                        const float* __restrict__ b_data, ushort_t* __restrict__ dst) {
  int stride = gridDim.x * 256;
  for (int i = blockIdx.x * 256 + threadIdx.x; i < 320 * 128; i += stride) {
    int seg = i >> 6, q = i & 63;
    int r = (seg >> 5) * 16 + (q & 15);
    int k = (seg & 31) * 32 + (q >> 4) * 8;
    const float* s = nullptr;
    if (r < 288) s = time_table + (size_t)r * 1024 + k;
    else if (r < 295) s = day_table + (size_t)(r - 288) * 1024 + k;
    else if (r == 295) s = b_data + k;
    bf16x8 o;
    #pragma unroll
    for (int j = 0; j < 8; ++j) o[j] = s ? f2b(s[j]) : (short)0;
    *(bf16x8*)(dst + (size_t)i * 8) = o;
  }
}
__global__ void pack_ae(const float* __restrict__ data, ushort_t* __restrict__ Ap) {
  int stride = gridDim.x * 256;
  const int total = (11776 / 16) * 11 * 64;
  for (int i = blockIdx.x * 256 + threadIdx.x; i < total; i += stride) {
    int seg = i >> 6, q = i & 63;
    int m = (seg / 11) * 16 + (q & 15);
    int k = (seg % 11) * 32 + (q >> 4) * 8;
    int b = m / TM1, t = m - b * TM1;
    const float* s = data + ((size_t)b * T_ + t) * OUT_;
    bf16x8 o;
    #pragma unroll
    for (int j = 0; j < 8; ++j) {
      int kk = k + j;
      o[j] = (kk < OUT_) ? f2b(s[kk]) : (short)0;
    }
    *(bf16x8*)(Ap + (size_t)i * 8) = o;
  }
}
__global__ void pack_dc(const float* __restrict__ data, ushort_t* __restrict__ DCp,
                        float* __restrict__ DC) {
  int stride = gridDim.x * 256;
  const int total = (512 / 16) * 11 * 64;
  for (int i = blockIdx.x * 256 + threadIdx.x; i < total; i += stride) {
    int seg = i >> 6, q = i & 63;
    int b = (seg / 11) * 16 + (q & 15);
    int k = (seg % 11) * 32 + (q >> 4) * 8;
    const float* s = data + ((size_t)b * T_ + (T_ - 1)) * OUT_;
    bf16x8 o;
    #pragma unroll
    for (int j = 0; j < 8; ++j) {
      int kk = k + j;
      float v = (kk < OUT_) ? s[kk] : 0.f;
      o[j] = f2b(v);
      if (kk < OUT_) DC[(size_t)b * OUT_ + kk] = v;
    }
    *(bf16x8*)(DCp + (size_t)i * 8) = o;
  }
}

extern "C" void kernel_launch(void* const* d_in, const int* in_sizes, int n_in,
                              void* d_out, int out_size, void* d_ws, size_t ws_size,
                              hipStream_t stream) {
  const float* data       = (const float*)d_in[0];
  const int*   timev      = (const int*)  d_in[1];
  const int*   weekday    = (const int*)  d_in[2];
  const float* w_data     = (const float*)d_in[3];
  const float* b_data     = (const float*)d_in[4];
  const float* time_table = (const float*)d_in[5];
  const float* day_table  = (const float*)d_in[6];
  const float* enc_Wih    = (const float*)d_in[7];
  const float* enc_Whh    = (const float*)d_in[8];
  const float* enc_bih    = (const float*)d_in[9];
  const float* enc_bhh    = (const float*)d_in[10];
  const float* dec_Wih    = (const float*)d_in[11];
  const float* dec_Whh    = (const float*)d_in[12];
  const float* dec_bih    = (const float*)d_in[13];
  const float* dec_bhh    = (const float*)d_in[14];
  const float* w_mlp      = (const float*)d_in[15];
  const float* b_mlp      = (const float*)d_in[16];
  float* out = (float*)d_out;

  char* base = (char*)d_ws;
  size_t o = 0;
  auto take = [&](size_t bytes) { void* p = base + o; o = (o + bytes + 511) & ~(size_t)511; return p; };
  const size_t WSZ = (size_t)6144 * 1024 * 2;
  ushort_t* Wih_e = (ushort_t*)take(WSZ);
  ushort_t* Whh_e = (ushort_t*)take(WSZ);
  ushort_t* Wih_d = (ushort_t*)take(WSZ);
  ushort_t* Whh_d = (ushort_t*)take(WSZ);
  ushort_t* WdTk  = (ushort_t*)take((size_t)384 * 1024 * 2);
  ushort_t* WmT   = (ushort_t*)take((size_t)384 * 1024 * 2);
  ushort_t* CTpk  = (ushort_t*)take((size_t)320 * 1024 * 2);
  ushort_t* W0ep  = (ushort_t*)take((size_t)3072 * 352 * 2);
  ushort_t* W0dp  = (ushort_t*)take((size_t)3072 * 352 * 2);
  float*    CTe   = (float*)take((size_t)320 * 3072 * 4);
  float*    CTd   = (float*)take((size_t)320 * 3072 * 4);
  float*    CBe   = (float*)take((size_t)512 * 3072 * 4);
  float*    CBd   = (float*)take((size_t)512 * 3072 * 4);
  ushort_t* Ap    = (ushort_t*)take((size_t)11776 * 352 * 2);
  ushort_t* Xp    = (ushort_t*)take((size_t)23 * 512 * 1024 * 2);
  ushort_t* GXbuf = (ushort_t*)take((size_t)23 * 512 * 3072 * 2);
  ushort_t* DCp   = (ushort_t*)take((size_t)512 * 352 * 2);
  float*    DC    = (float*)take((size_t)512 * OUT_ * 4);
  float*    Hfb   = (float*)take((size_t)4 * 512 * 1024 * 4 + (size_t)4 * 512 * 1024 * 2);
  if (o > ws_size) return; // ~200 MB required

  float* Hf0[2], *Hf1[2]; ushort_t* Hp0[2], *Hp1[2];
  ushort_t* Hpb = (ushort_t*)(Hfb + (size_t)4 * 512 * 1024);
  for (int p = 0; p < 2; ++p) {
    Hf0[p] = Hfb + (size_t)p * 512 * 1024;
    Hf1[p] = Hfb + (size_t)(2 + p) * 512 * 1024;
    Hp0[p] = Hpb + (size_t)p * 512 * 1024;
    Hp1[p] = Hpb + (size_t)(2 + p) * 512 * 1024;
  }

  const size_t WLAYER = (size_t)3072 * 1024;

  // ---- packs
  pack_k1024<<<3072, 256, 0, stream>>>(enc_Wih, Wih_e, 6144 * 128, 6144);
  pack_k1024<<<3072, 256, 0, stream>>>(enc_Whh, Whh_e, 6144 * 128, 6144);
  pack_k1024<<<3072, 256, 0, stream>>>(dec_Wih, Wih_d, 6144 * 128, 6144);
  pack_k1024<<<3072, 256, 0, stream>>>(dec_Whh, Whh_d, 6144 * 128, 6144);
  pack_k1024<<<192, 256, 0, stream>>>(w_data, WdTk, 384 * 128, OUT_);
  pack_wm<<<192, 256, 0, stream>>>(w_mlp, WmT);
  pack_ct<<<160, 256, 0, stream>>>(time_table, day_table, b_data, CTpk);
  pack_ae<<<2048, 256, 0, stream>>>(data, Ap);
  pack_dc<<<88, 256, 0, stream>>>(data, DCp, DC);

  // ---- combined-weight setup GEMMs
  gemm64<0><<<dim3(48, 6), 256, 0, stream>>>(Wih_e, WdTk, 32, nullptr, 0, W0ep, nullptr, nullptr, nullptr);
  gemm64<0><<<dim3(48, 6), 256, 0, stream>>>(Wih_d, WdTk, 32, nullptr, 0, W0dp, nullptr, nullptr, nullptr);
  gemm64<1><<<dim3(5, 48), 256, 0, stream>>>(CTpk, Wih_e, 32, nullptr, 0, nullptr, CTe, nullptr, nullptr);
  gemm64<1><<<dim3(5, 48), 256, 0, stream>>>(CTpk, Wih_d, 32, nullptr, 0, nullptr, CTd, nullptr, nullptr);
  build_cb<<<6144, 256, 0, stream>>>(CTe, enc_bih, weekday, CBe);
  build_cb<<<6144, 256, 0, stream>>>(CTd, dec_bih, weekday, CBd);

  // ---- encoder layer-0 gx (embed folded)
  gemm_gx0_enc<<<dim3(92, 24), 256, 0, stream>>>(Ap, W0ep, CTe, CBe, timev, GXbuf);

  // ---- zero initial hidden states
  hipMemsetAsync(Hf0[0], 0, (size_t)512 * 1024 * 4, stream);
  hipMemsetAsync(Hf1[0], 0, (size_t)512 * 1024 * 4, stream);
  hipMemsetAsync(Hp0[0], 0, (size_t)512 * 1024 * 2, stream);
  hipMemsetAsync(Hp1[0], 0, (size_t)512 * 1024 * 2, stream);

  // ---- diagonal encoder (1024 blocks, XCD-swizzled, direct-register cells)
  int p0 = 0, p1 = 0;
  for (int k = 0; k <= TM1; ++k) {
    enc_diag<<<1024, 256, 0, stream>>>(k,
        Hp0[p0], Hf0[p0], Hf0[1 - p0], Hp0[1 - p0], Whh_e, enc_bhh, GXbuf, Xp,
        Hp1[p1], Hf1[p1], Hf1[1 - p1], Hp1[1 - p1],
        Wih_e + WLAYER, Whh_e + WLAYER, enc_bih + 3072, enc_bhh + 3072);
    if (k < TM1) p0 ^= 1;
    if (k >= 1)  p1 ^= 1;
  }

  // ---- decoder (512-block cells, XCD-swizzled, direct-register)
  for (int s = 0; s < HORIZON_; ++s) {
    dec_cell0<<<512, 256, 0, stream>>>(
        DCp, Hp0[p0], Hf0[p0], W0dp, Whh_d, dec_bhh, CTd, CBd, timev, s,
        Hf0[1 - p0], Hp0[1 - p0]);
    p0 ^= 1;
    gru_cell32<<<512, 256, 0, stream>>>(
        Hp0[p0], Hp1[p1], Hf1[p1],
        Wih_d + WLAYER, Whh_d + WLAYER, dec_bih + 3072, dec_bhh + 3072,
        Hf1[1 - p1], Hp1[1 - p1]);
    p1 ^= 1;
    gemm64<3><<<dim3(8, 6), 256, 0, stream>>>(
        Hp1[p1], WmT, 32, b_mlp, s, nullptr, DC, out, DCp);
  }
}

// Round 10
// 1405.476 us; speedup vs baseline: 1.1126x; 1.1126x over previous
//
#include <hip/hip_runtime.h>
#include <math.h>

#define B_ 512
#define T_ 24
#define TM1 23
#define D_ 1024
#define OUT_ 325
#define HORIZON_ 12

typedef unsigned short ushort_t;
typedef __attribute__((ext_vector_type(8))) short bf16x8;
typedef __attribute__((ext_vector_type(4))) float f32x4;

#define MFMA16(a, b, c) __builtin_amdgcn_mfma_f32_16x16x32_bf16((a), (b), (c), 0, 0, 0)

__device__ __forceinline__ ushort_t f2b(float f) {
  union { float f; unsigned u; } v; v.f = f;
  unsigned r = (v.u + 0x7fffu + ((v.u >> 16) & 1u)) >> 16;
  return (ushort_t)r;
}
__device__ __forceinline__ float b2f(ushort_t s) {
  union { unsigned u; float f; } v; v.u = ((unsigned)s) << 16;
  return v.f;
}

// 16-row-granular packed fragment layout for (M x K) bf16, M%16==0, K%32==0.
__device__ __forceinline__ size_t pidx16(int m, int k, int K) {
  return (((size_t)(m >> 4) * (K >> 5) + (k >> 5)) * 64
          + ((m & 15) + (((k >> 3) & 3) << 4))) * 8 + (k & 7);
}

#define GLOAD16(src, dst) \
  __builtin_amdgcn_global_load_lds((const __attribute__((address_space(1))) void*)(src), \
                                   (__attribute__((address_space(3))) void*)(dst), 16, 0, 0)

// =============== 3-stage diagonal encoder step (uniform light blocks) ===============
// 1536 blocks: z = bid>>9 (0..2), bx = (bid>>5)&15, by = bid&31 (bid%8=by%8 -> XCD aff)
// z=0: layer-0 gh-cell at t=k (gx precomputed in GXbuf row-major, bih folded)
// z=1: gx1 GEMM for t=k-1: GX1p[(k-1)&1] = Y0[k-1]@Wih1^T + bih1 (packed bf16)
// z=2: layer-1 gh-cell at t=k-2 (gx from GX1p[k&1], bih folded)
// All stages: identical 8-seg staging, 4 loads + 3 MFMAs per wave per kb.
__global__ __launch_bounds__(256) void enc_diag(
    int k,
    const ushort_t* __restrict__ Hp0, const float* __restrict__ Hf0,
    float* __restrict__ Hf0o, ushort_t* __restrict__ Hp0o,
    const ushort_t* __restrict__ Whh0, const float* __restrict__ bhh0,
    const ushort_t* __restrict__ GXbuf, ushort_t* __restrict__ Y0p,
    const ushort_t* __restrict__ Wih1, const float* __restrict__ bih1,
    ushort_t* __restrict__ GX1p,   // 2 slots x (512x3072) packed
    const ushort_t* __restrict__ Hp1, const float* __restrict__ Hf1,
    float* __restrict__ Hf1o, ushort_t* __restrict__ Hp1o,
    const ushort_t* __restrict__ Whh1, const float* __restrict__ bhh1)
{
  __shared__ ushort_t lds[2][8 * 512]; // 16 KB
  const int tid = threadIdx.x, lane = tid & 63, w = tid >> 6;
  const int bid = blockIdx.x;
  const int z = bid >> 9, bx = (bid >> 5) & 15, by = bid & 31;
  const int wm = w >> 1, wn = w & 1;
  const int d = by * 32 + wn * 16 + (lane & 15);

  const ushort_t *Abase, *Bbase;
  if (z == 0) {
    if (k >= TM1) return;
    Abase = Hp0; Bbase = Whh0;
  } else if (z == 1) {
    if (k < 1 || k > TM1) return;
    Abase = Y0p + (size_t)(k - 1) * 512 * 1024; Bbase = Wih1;
  } else {
    if (k < 2) return;
    Abase = Hp1; Bbase = Whh1;
  }

  f32x4 acc[3] = {};
  auto stage = [&](int buf, int kb) {
    #pragma unroll
    for (int r = 0; r < 2; ++r) {
      int s = w * 2 + r;
      const ushort_t* src;
      if (s < 2) src = Abase + ((size_t)(((bx * 32 + s * 16) >> 4) * 32 + kb)) * 512 + lane * 8;
      else { int g = (s - 2) >> 1, hf = (s - 2) & 1;
        src = Bbase + ((size_t)((g * 64 + by * 2 + hf) * 32 + kb)) * 512 + lane * 8; }
      GLOAD16(src, &lds[buf][s * 512 + lane * 8]);
    }
  };
  stage(0, 0); __syncthreads();
  int cur = 0;
  for (int kb = 0; kb < 32; ++kb) {
    if (kb + 1 < 32) stage(cur ^ 1, kb + 1);
    const ushort_t* L = lds[cur];
    bf16x8 a = *(const bf16x8*)(L + wm * 512 + lane * 8);
    #pragma unroll
    for (int g = 0; g < 3; ++g) {
      bf16x8 b = *(const bf16x8*)(L + (2 + g * 2 + wn) * 512 + lane * 8);
      acc[g] = MFMA16(a, b, acc[g]);
    }
    __syncthreads(); cur ^= 1;
  }

  if (z == 1) {
    ushort_t* G = GX1p + (size_t)((k - 1) & 1) * 512 * 3072;
    #pragma unroll
    for (int q = 0; q < 4; ++q) {
      int m = bx * 32 + wm * 16 + ((lane >> 4) << 2) + q;
      #pragma unroll
      for (int g = 0; g < 3; ++g) {
        int n = g * 1024 + d;
        G[pidx16(m, n, 3072)] = f2b(acc[g][q] + bih1[n]);
      }
    }
    return;
  }

  // z==0 / z==2: gate epilogue (gx has bih folded already)
  const float* bhh = (z == 0) ? bhh0 : bhh1;
  const float* Hf  = (z == 0) ? Hf0 : Hf1;
  float* HfO       = (z == 0) ? Hf0o : Hf1o;
  ushort_t* HpO    = (z == 0) ? Hp0o : Hp1o;
  const float bh_r = bhh[d], bh_z = bhh[D_ + d], bh_n = bhh[2 * D_ + d];
  const ushort_t* GXrow = (z == 0) ? (GXbuf + (size_t)k * 512 * 3072) : nullptr;
  const ushort_t* G2 = (z == 2) ? (GX1p + (size_t)(k & 1) * 512 * 3072) : nullptr;
  ushort_t* Seqp = (z == 0) ? (Y0p + (size_t)k * 512 * 1024) : nullptr;
  #pragma unroll
  for (int q = 0; q < 4; ++q) {
    int m = bx * 32 + wm * 16 + ((lane >> 4) << 2) + q;
    float gx_r, gx_z, gx_n;
    if (z == 0) {
      const ushort_t* gxp = GXrow + (size_t)m * 3072 + d;
      gx_r = b2f(gxp[0]); gx_z = b2f(gxp[D_]); gx_n = b2f(gxp[2 * D_]);
    } else {
      gx_r = b2f(G2[pidx16(m, d, 3072)]);
      gx_z = b2f(G2[pidx16(m, D_ + d, 3072)]);
      gx_n = b2f(G2[pidx16(m, 2 * D_ + d, 3072)]);
    }
    float rr = 1.f / (1.f + __expf(-(gx_r + acc[0][q] + bh_r)));
    float zz = 1.f / (1.f + __expf(-(gx_z + acc[1][q] + bh_z)));
    float nn = tanhf(gx_n + rr * (acc[2][q] + bh_n));
    float h = Hf[(size_t)m * D_ + d];
    float hnew = (1.f - zz) * nn + zz * h;
    HfO[(size_t)m * D_ + d] = hnew;
    ushort_t hb = f2b(hnew);
    size_t pi = pidx16(m, d, D_);
    HpO[pi] = hb;
    if (z == 0) Seqp[pi] = hb;
  }
}

// =============== decoder layer-0 cell, BM=32, swizzled: fused gx0 (K=352) + gh ======
__global__ __launch_bounds__(256) void dec_cell0(
    const ushort_t* __restrict__ DCp, const ushort_t* __restrict__ Hp,
    const float* __restrict__ Hf,
    const ushort_t* __restrict__ W0dp, const ushort_t* __restrict__ Whh0,
    const float* __restrict__ bhh0,
    const float* __restrict__ CTt, const float* __restrict__ CBd,
    const int* __restrict__ timev, int step,
    float* __restrict__ Hf_out, ushort_t* __restrict__ Hp_out)
{
  __shared__ ushort_t lds[2][16 * 512];
  const int tid = threadIdx.x, lane = tid & 63, w = tid >> 6;
  const int bid = blockIdx.x;
  const int bx = bid >> 5, by = bid & 31;
  const int wm = w >> 1, wn = w & 1;
  const int d = by * 32 + wn * 16 + (lane & 15);
  f32x4 accx[3] = {}, acch[3] = {};

  auto stage_h = [&](int buf, int kb) {  // segs {2,3,10..15}
    #pragma unroll
    for (int r = 0; r < 2; ++r) {
      int s = (w == 0) ? (2 + r) : (8 + w * 2 + r);
      const ushort_t* src;
      if (s < 4) src = Hp + ((size_t)(((bx * 32 + (s - 2) * 16) >> 4) * 32 + kb)) * 512 + lane * 8;
      else { int g = (s - 10) >> 1, hf = (s - 10) & 1;
        src = Whh0 + ((size_t)((g * 64 + by * 2 + hf) * 32 + kb)) * 512 + lane * 8; }
      GLOAD16(src, &lds[buf][s * 512 + lane * 8]);
    }
  };
  auto stage_x = [&](int buf, int kb) {  // segs {0,1,4..9}, kb<11
    #pragma unroll
    for (int r = 0; r < 2; ++r) {
      int s = (w == 0) ? r : (2 + w * 2 + r);
      const ushort_t* src;
      if (s < 2) src = DCp + ((size_t)(((bx * 32 + s * 16) >> 4) * 11 + kb)) * 512 + lane * 8;
      else { int g = (s - 4) >> 1, hf = (s - 4) & 1;
        src = W0dp + ((size_t)((g * 64 + by * 2 + hf) * 11 + kb)) * 512 + lane * 8; }
      GLOAD16(src, &lds[buf][s * 512 + lane * 8]);
    }
  };

  stage_h(0, 0); stage_x(0, 0);
  __syncthreads();
  int cur = 0;
  for (int kb = 0; kb < 32; ++kb) {
    if (kb + 1 < 32) {
      stage_h(cur ^ 1, kb + 1);
      if (kb + 1 < 11) stage_x(cur ^ 1, kb + 1);
    }
    const ushort_t* L = lds[cur];
    bf16x8 ah = *(const bf16x8*)(L + (2 + wm) * 512 + lane * 8);
    if (kb < 11) {
      bf16x8 ax = *(const bf16x8*)(L + (0 + wm) * 512 + lane * 8);
      #pragma unroll
      for (int g = 0; g < 3; ++g) {
        bf16x8 bxw = *(const bf16x8*)(L + (4 + g * 2 + wn) * 512 + lane * 8);
        accx[g] = MFMA16(ax, bxw, accx[g]);
      }
    }
    #pragma unroll
    for (int g = 0; g < 3; ++g) {
      bf16x8 bhw = *(const bf16x8*)(L + (10 + g * 2 + wn) * 512 + lane * 8);
      acch[g] = MFMA16(ah, bhw, acch[g]);
    }
    __syncthreads(); cur ^= 1;
  }

  const float bh_r = bhh0[d], bh_z = bhh0[D_ + d], bh_n = bhh0[2 * D_ + d];
  #pragma unroll
  for (int q = 0; q < 4; ++q) {
    int m = bx * 32 + wm * 16 + ((lane >> 4) << 2) + q;
    int ti = (timev[m * T_ + (T_ - 1)] + step) % 288;
    const float* ctt = CTt + (size_t)ti * 3072;
    const float* cb  = CBd + (size_t)m * 3072;
    float gx_r = accx[0][q] + ctt[d] + cb[d];
    float gx_z = accx[1][q] + ctt[D_ + d] + cb[D_ + d];
    float gx_n = accx[2][q] + ctt[2 * D_ + d] + cb[2 * D_ + d];
    float rr = 1.f / (1.f + __expf(-(gx_r + acch[0][q] + bh_r)));
    float zz = 1.f / (1.f + __expf(-(gx_z + acch[1][q] + bh_z)));
    float nn = tanhf(gx_n + rr * (acch[2][q] + bh_n));
    float h = Hf[(size_t)m * D_ + d];
    float hnew = (1.f - zz) * nn + zz * h;
    Hf_out[(size_t)m * D_ + d] = hnew;
    Hp_out[pidx16(m, d, D_)] = f2b(hnew);
  }
}

// =============== decoder layer-1 full cell, BM=32, swizzled ===============
__global__ __launch_bounds__(256) void gru_cell32(
    const ushort_t* __restrict__ Xp_, const ushort_t* __restrict__ Hp,
    const float* __restrict__ Hf,
    const ushort_t* __restrict__ Wih_l, const ushort_t* __restrict__ Whh_l,
    const float* __restrict__ bih_l, const float* __restrict__ bhh_l,
    float* __restrict__ Hf_out, ushort_t* __restrict__ Hp_out)
{
  __shared__ ushort_t lds[2][16 * 512];
  const int tid = threadIdx.x, lane = tid & 63, w = tid >> 6;
  const int bid = blockIdx.x;
  const int bx = bid >> 5, by = bid & 31;
  const int wm = w >> 1, wn = w & 1;
  const int d = by * 32 + wn * 16 + (lane & 15);
  f32x4 accx[3] = {}, acch[3] = {};

  auto stage = [&](int buf, int kb) {
    #pragma unroll
    for (int r = 0; r < 4; ++r) {
      int s = w * 4 + r;
      const ushort_t* src;
      if (s < 2) src = Xp_ + ((size_t)(((bx * 32 + s * 16) >> 4) * 32 + kb)) * 512 + lane * 8;
      else if (s < 4) src = Hp + ((size_t)(((bx * 32 + (s - 2) * 16) >> 4) * 32 + kb)) * 512 + lane * 8;
      else if (s < 10) { int g = (s - 4) >> 1, hf = (s - 4) & 1;
        src = Wih_l + ((size_t)((g * 64 + by * 2 + hf) * 32 + kb)) * 512 + lane * 8; }
      else { int g = (s - 10) >> 1, hf = (s - 10) & 1;
        src = Whh_l + ((size_t)((g * 64 + by * 2 + hf) * 32 + kb)) * 512 + lane * 8; }
      GLOAD16(src, &lds[buf][s * 512 + lane * 8]);
    }
  };

  stage(0, 0); __syncthreads();
  int cur = 0;
  for (int kb = 0; kb < 32; ++kb) {
    if (kb + 1 < 32) stage(cur ^ 1, kb + 1);
    const ushort_t* L = lds[cur];
    bf16x8 ax = *(const bf16x8*)(L + (0 + wm) * 512 + lane * 8);
    bf16x8 ah = *(const bf16x8*)(L + (2 + wm) * 512 + lane * 8);
    #pragma unroll
    for (int g = 0; g < 3; ++g) {
      bf16x8 bxw = *(const bf16x8*)(L + (4 + g * 2 + wn) * 512 + lane * 8);
      bf16x8 bhw = *(const bf16x8*)(L + (10 + g * 2 + wn) * 512 + lane * 8);
      accx[g] = MFMA16(ax, bxw, accx[g]);
      acch[g] = MFMA16(ah, bhw, acch[g]);
    }
    __syncthreads(); cur ^= 1;
  }

  const float bi_r = bih_l[d], bi_z = bih_l[D_ + d], bi_n = bih_l[2 * D_ + d];
  const float bh_r = bhh_l[d], bh_z = bhh_l[D_ + d], bh_n = bhh_l[2 * D_ + d];
  #pragma unroll
  for (int q = 0; q < 4; ++q) {
    int m = bx * 32 + wm * 16 + ((lane >> 4) << 2) + q;
    float rr = 1.f / (1.f + __expf(-(accx[0][q] + bi_r + acch[0][q] + bh_r)));
    float zz = 1.f / (1.f + __expf(-(accx[1][q] + bi_z + acch[1][q] + bh_z)));
    float nn = tanhf(accx[2][q] + bi_n + rr * (acch[2][q] + bh_n));
    float h = Hf[(size_t)m * D_ + d];
    float hnew = (1.f - zz) * nn + zz * h;
    Hf_out[(size_t)m * D_ + d] = hnew;
    Hp_out[pidx16(m, d, D_)] = f2b(hnew);
  }
}

// =============== encoder layer-0 gx: 128-tile, K=352, padded LDS-transpose epilogue ==
__global__ __launch_bounds__(256) void gemm_gx0_enc(
    const ushort_t* __restrict__ Ap, const ushort_t* __restrict__ W0p,
    const float* __restrict__ CTt, const float* __restrict__ CBe,
    const int* __restrict__ timev,
    ushort_t* __restrict__ GX)
{
  __shared__ ushort_t lds[2][16 * 512];
  const int tid = threadIdx.x, lane = tid & 63, w = tid >> 6;
  const int bx = blockIdx.x, by = blockIdx.y;
  const int wm = w >> 1, wn = w & 1;
  f32x4 acc[4][4] = {};

  auto stage = [&](int buf, int kb) {
    #pragma unroll
    for (int r = 0; r < 4; ++r) {
      int s = r * 4 + w;
      const ushort_t* src = (s < 8)
          ? Ap  + ((size_t)((bx * 8 + s) * 11 + kb)) * 512 + lane * 8
          : W0p + ((size_t)((by * 8 + (s - 8)) * 11 + kb)) * 512 + lane * 8;
      GLOAD16(src, &lds[buf][s * 512 + lane * 8]);
    }
  };

  stage(0, 0); __syncthreads();
  int cur = 0;
  for (int kb = 0; kb < 11; ++kb) {
    if (kb + 1 < 11) stage(cur ^ 1, kb + 1);
    const ushort_t* L = lds[cur];
    bf16x8 af[4], bf[4];
    #pragma unroll
    for (int f = 0; f < 4; ++f) {
      af[f] = *(const bf16x8*)(L + (wm * 4 + f) * 512 + lane * 8);
      bf[f] = *(const bf16x8*)(L + (8 + wn * 4 + f) * 512 + lane * 8);
    }
    #pragma unroll
    for (int fm = 0; fm < 4; ++fm)
      #pragma unroll
      for (int fn = 0; fn < 4; ++fn)
        acc[fm][fn] = MFMA16(af[fm], bf[fn], acc[fm][fn]);
    __syncthreads(); cur ^= 1;
  }

  // epilogue: per-fm LDS transpose (row stride 132 f32 to avoid bank aliasing)
  float* fl = (float*)&lds[0][0]; // [32][132] f32 = 16.9 KB
  for (int fm = 0; fm < 4; ++fm) {
    #pragma unroll
    for (int q = 0; q < 4; ++q)
      #pragma unroll
      for (int fn = 0; fn < 4; ++fn)
        fl[(wm * 16 + ((lane >> 4) << 2) + q) * 132 + wn * 64 + fn * 16 + (lane & 15)]
            = acc[fm][fn][q];
    __syncthreads();
    #pragma unroll
    for (int it = 0; it < 2; ++it) {
      int idx = it * 256 + tid;
      int ml = idx >> 4, n0 = (idx & 15) * 8;
      int m = bx * 128 + (ml >> 4) * 64 + fm * 16 + (ml & 15);
      int b = m / 23, t = m - b * 23;
      int ti = timev[b * T_ + t] % 288;
      const float* ctt = CTt + (size_t)ti * 3072 + by * 128 + n0;
      const float* cb  = CBe + (size_t)b * 3072 + by * 128 + n0;
      const float* fr  = fl + ml * 132 + n0;
      bf16x8 o;
      #pragma unroll
      for (int j = 0; j < 8; ++j) o[j] = f2b(fr[j] + ctt[j] + cb[j]);
      *(bf16x8*)(GX + ((size_t)t * 512 + b) * 3072 + by * 128 + n0) = o;
    }
    __syncthreads();
  }
}

// =============== generic 64-tile GEMM with epilogues ===============
template<int EPI>
__global__ __launch_bounds__(256) void gemm64(
    const ushort_t* __restrict__ Ap, const ushort_t* __restrict__ Wp, int K32,
    const float* __restrict__ bias, int step,
    ushort_t* __restrict__ outp, float* __restrict__ outf,
    float* __restrict__ dout, ushort_t* __restrict__ DCp)
{
  __shared__ ushort_t lds[2][8 * 512];
  const int tid = threadIdx.x, lane = tid & 63, w = tid >> 6;
  const int bx = blockIdx.x, by = blockIdx.y;
  const int wm = w >> 1, wn = w & 1;
  f32x4 acc[2][2] = {};

  auto stage = [&](int buf, int kb) {
    #pragma unroll
    for (int r = 0; r < 2; ++r) {
      int s = r * 4 + w;
      const ushort_t* src = (s < 4)
          ? Ap + ((size_t)((bx * 4 + s) * K32 + kb)) * 512 + lane * 8
          : Wp + ((size_t)((by * 4 + (s - 4)) * K32 + kb)) * 512 + lane * 8;
      GLOAD16(src, &lds[buf][s * 512 + lane * 8]);
    }
  };

  stage(0, 0); __syncthreads();
  int cur = 0;
  for (int kb = 0; kb < K32; ++kb) {
    if (kb + 1 < K32) stage(cur ^ 1, kb + 1);
    const ushort_t* L = lds[cur];
    bf16x8 af[2], bf[2];
    #pragma unroll
    for (int f = 0; f < 2; ++f) {
      af[f] = *(const bf16x8*)(L + (wm * 2 + f) * 512 + lane * 8);
      bf[f] = *(const bf16x8*)(L + (4 + wn * 2 + f) * 512 + lane * 8);
    }
    #pragma unroll
    for (int fm = 0; fm < 2; ++fm)
      #pragma unroll
      for (int fn = 0; fn < 2; ++fn)
        acc[fm][fn] = MFMA16(af[fm], bf[fn], acc[fm][fn]);
    __syncthreads(); cur ^= 1;
  }

  #pragma unroll
  for (int fm = 0; fm < 2; ++fm) {
    #pragma unroll
    for (int q = 0; q < 4; ++q) {
      int m = bx * 64 + wm * 32 + fm * 16 + ((lane >> 4) << 2) + q;
      #pragma unroll
      for (int fn = 0; fn < 2; ++fn) {
        int n = by * 64 + wn * 32 + fn * 16 + (lane & 15);
        float v = acc[fm][fn][q];
        if (EPI == 0) {
          if (n < 352) outp[pidx16(m, n, 352)] = f2b(v);
        } else if (EPI == 1) {
          outf[(size_t)m * 3072 + n] = v;
        } else {
          if (n < OUT_) {
            v += bias[n] + outf[(size_t)m * OUT_ + n];
            dout[((size_t)m * HORIZON_ + step) * OUT_ + n] = v;
            outf[(size_t)m * OUT_ + n] = v;
            DCp[pidx16(m, n, 352)] = f2b(v);
          }
        }
      }
    }
  }
}

// =============== CB = day' + b_data' + bih (per batch row) ===============
__global__ void build_cb(const float* __restrict__ CT, const float* __restrict__ bih0,
                         const int* __restrict__ weekday, float* __restrict__ CB)
{
  int idx = blockIdx.x * 256 + threadIdx.x;
  if (idx >= 512 * 3072) return;
  int b = idx / 3072, n = idx - b * 3072;
  CB[idx] = CT[(size_t)(288 + weekday[b]) * 3072 + n] + CT[(size_t)295 * 3072 + n] + bih0[n];
}

// ================= dest-major pack kernels =================
__global__ void pack_k1024(const float* __restrict__ src, ushort_t* __restrict__ dst,
                           int total, int Mvalid) {
  int stride = gridDim.x * 256;
  for (int i = blockIdx.x * 256 + threadIdx.x; i < total; i += stride) {
    int seg = i >> 6, q = i & 63;
    int m = (seg >> 5) * 16 + (q & 15);
    int k = (seg & 31) * 32 + (q >> 4) * 8;
    bf16x8 o;
    if (m < Mvalid) {
      const float* s = src + (size_t)m * 1024 + k;
      float4 v0 = *(const float4*)s, v1 = *(const float4*)(s + 4);
      o[0] = f2b(v0.x); o[1] = f2b(v0.y); o[2] = f2b(v0.z); o[3] = f2b(v0.w);
      o[4] = f2b(v1.x); o[5] = f2b(v1.y); o[6] = f2b(v1.z); o[7] = f2b(v1.w);
    } else o = bf16x8{0,0,0,0,0,0,0,0};
    *(bf16x8*)(dst + (size_t)i * 8) = o;
  }
}
__global__ void pack_wm(const float* __restrict__ w_mlp, ushort_t* __restrict__ dst) {
  int stride = gridDim.x * 256;
  for (int i = blockIdx.x * 256 + threadIdx.x; i < 384 * 128; i += stride) {
    int seg = i >> 6, q = i & 63;
    int n = (seg >> 5) * 16 + (q & 15);
    int k = (seg & 31) * 32 + (q >> 4) * 8;
    bf16x8 o;
    #pragma unroll
    for (int j = 0; j < 8; ++j)
      o[j] = (n < OUT_) ? f2b(w_mlp[(size_t)(k + j) * OUT_ + n]) : (short)0;
    *(bf16x8*)(dst + (size_t)i * 8) = o;
  }
}
__global__ void pack_ct(const float* __restrict__ time_table, const float* __restrict__ day_table,
                        const float* __restrict__ b_data, ushort_t* __restrict__ dst) {
  int stride = gridDim.x * 256;
  for (int i = blockIdx.x * 256 + threadIdx.x; i < 320 * 128; i += stride) {
    int seg = i >> 6, q = i & 63;
    int r = (seg >> 5) * 16 + (q & 15);
    int k = (seg & 31) * 32 + (q >> 4) * 8;
    const float* s = nullptr;
    if (r < 288) s = time_table + (size_t)r * 1024 + k;
    else if (r < 295) s = day_table + (size_t)(r - 288) * 1024 + k;
    else if (r == 295) s = b_data + k;
    bf16x8 o;
    #pragma unroll
    for (int j = 0; j < 8; ++j) o[j] = s ? f2b(s[j]) : (short)0;
    *(bf16x8*)(dst + (size_t)i * 8) = o;
  }
}
__global__ void pack_ae(const float* __restrict__ data, ushort_t* __restrict__ Ap) {
  int stride = gridDim.x * 256;
  const int total = (11776 / 16) * 11 * 64;
  for (int i = blockIdx.x * 256 + threadIdx.x; i < total; i += stride) {
    int seg = i >> 6, q = i & 63;
    int m = (seg / 11) * 16 + (q & 15);
    int k = (seg % 11) * 32 + (q >> 4) * 8;
    int b = m / TM1, t = m - b * TM1;
    const float* s = data + ((size_t)b * T_ + t) * OUT_;
    bf16x8 o;
    #pragma unroll
    for (int j = 0; j < 8; ++j) {
      int kk = k + j;
      o[j] = (kk < OUT_) ? f2b(s[kk]) : (short)0;
    }
    *(bf16x8*)(Ap + (size_t)i * 8) = o;
  }
}
__global__ void pack_dc(const float* __restrict__ data, ushort_t* __restrict__ DCp,
                        float* __restrict__ DC) {
  int stride = gridDim.x * 256;
  const int total = (512 / 16) * 11 * 64;
  for (int i = blockIdx.x * 256 + threadIdx.x; i < total; i += stride) {
    int seg = i >> 6, q = i & 63;
    int b = (seg / 11) * 16 + (q & 15);
    int k = (seg % 11) * 32 + (q >> 4) * 8;
    const float* s = data + ((size_t)b * T_ + (T_ - 1)) * OUT_;
    bf16x8 o;
    #pragma unroll
    for (int j = 0; j < 8; ++j) {
      int kk = k + j;
      float v = (kk < OUT_) ? s[kk] : 0.f;
      o[j] = f2b(v);
      if (kk < OUT_) DC[(size_t)b * OUT_ + kk] = v;
    }
    *(bf16x8*)(DCp + (size_t)i * 8) = o;
  }
}

extern "C" void kernel_launch(void* const* d_in, const int* in_sizes, int n_in,
                              void* d_out, int out_size, void* d_ws, size_t ws_size,
                              hipStream_t stream) {
  const float* data       = (const float*)d_in[0];
  const int*   timev      = (const int*)  d_in[1];
  const int*   weekday    = (const int*)  d_in[2];
  const float* w_data     = (const float*)d_in[3];
  const float* b_data     = (const float*)d_in[4];
  const float* time_table = (const float*)d_in[5];
  const float* day_table  = (const float*)d_in[6];
  const float* enc_Wih    = (const float*)d_in[7];
  const float* enc_Whh    = (const float*)d_in[8];
  const float* enc_bih    = (const float*)d_in[9];
  const float* enc_bhh    = (const float*)d_in[10];
  const float* dec_Wih    = (const float*)d_in[11];
  const float* dec_Whh    = (const float*)d_in[12];
  const float* dec_bih    = (const float*)d_in[13];
  const float* dec_bhh    = (const float*)d_in[14];
  const float* w_mlp      = (const float*)d_in[15];
  const float* b_mlp      = (const float*)d_in[16];
  float* out = (float*)d_out;

  char* base = (char*)d_ws;
  size_t o = 0;
  auto take = [&](size_t bytes) { void* p = base + o; o = (o + bytes + 511) & ~(size_t)511; return p; };
  const size_t WSZ = (size_t)6144 * 1024 * 2;
  ushort_t* Wih_e = (ushort_t*)take(WSZ);
  ushort_t* Whh_e = (ushort_t*)take(WSZ);
  ushort_t* Wih_d = (ushort_t*)take(WSZ);
  ushort_t* Whh_d = (ushort_t*)take(WSZ);
  ushort_t* WdTk  = (ushort_t*)take((size_t)384 * 1024 * 2);
  ushort_t* WmT   = (ushort_t*)take((size_t)384 * 1024 * 2);
  ushort_t* CTpk  = (ushort_t*)take((size_t)320 * 1024 * 2);
  ushort_t* W0ep  = (ushort_t*)take((size_t)3072 * 352 * 2);
  ushort_t* W0dp  = (ushort_t*)take((size_t)3072 * 352 * 2);
  float*    CTe   = (float*)take((size_t)320 * 3072 * 4);
  float*    CTd   = (float*)take((size_t)320 * 3072 * 4);
  float*    CBe   = (float*)take((size_t)512 * 3072 * 4);
  float*    CBd   = (float*)take((size_t)512 * 3072 * 4);
  ushort_t* Ap    = (ushort_t*)take((size_t)11776 * 352 * 2);
  ushort_t* Xp    = (ushort_t*)take((size_t)23 * 512 * 1024 * 2);
  ushort_t* GXbuf = (ushort_t*)take((size_t)23 * 512 * 3072 * 2);
  ushort_t* GX1p  = (ushort_t*)take((size_t)2 * 512 * 3072 * 2);
  ushort_t* DCp   = (ushort_t*)take((size_t)512 * 352 * 2);
  float*    DC    = (float*)take((size_t)512 * OUT_ * 4);
  float*    Hfb   = (float*)take((size_t)4 * 512 * 1024 * 4 + (size_t)4 * 512 * 1024 * 2);
  if (o > ws_size) return; // ~207 MB required

  float* Hf0[2], *Hf1[2]; ushort_t* Hp0[2], *Hp1[2];
  ushort_t* Hpb = (ushort_t*)(Hfb + (size_t)4 * 512 * 1024);
  for (int p = 0; p < 2; ++p) {
    Hf0[p] = Hfb + (size_t)p * 512 * 1024;
    Hf1[p] = Hfb + (size_t)(2 + p) * 512 * 1024;
    Hp0[p] = Hpb + (size_t)p * 512 * 1024;
    Hp1[p] = Hpb + (size_t)(2 + p) * 512 * 1024;
  }

  const size_t WLAYER = (size_t)3072 * 1024;

  // ---- packs
  pack_k1024<<<3072, 256, 0, stream>>>(enc_Wih, Wih_e, 6144 * 128, 6144);
  pack_k1024<<<3072, 256, 0, stream>>>(enc_Whh, Whh_e, 6144 * 128, 6144);
  pack_k1024<<<3072, 256, 0, stream>>>(dec_Wih, Wih_d, 6144 * 128, 6144);
  pack_k1024<<<3072, 256, 0, stream>>>(dec_Whh, Whh_d, 6144 * 128, 6144);
  pack_k1024<<<192, 256, 0, stream>>>(w_data, WdTk, 384 * 128, OUT_);
  pack_wm<<<192, 256, 0, stream>>>(w_mlp, WmT);
  pack_ct<<<160, 256, 0, stream>>>(time_table, day_table, b_data, CTpk);
  pack_ae<<<2048, 256, 0, stream>>>(data, Ap);
  pack_dc<<<88, 256, 0, stream>>>(data, DCp, DC);

  // ---- combined-weight setup GEMMs
  gemm64<0><<<dim3(48, 6), 256, 0, stream>>>(Wih_e, WdTk, 32, nullptr, 0, W0ep, nullptr, nullptr, nullptr);
  gemm64<0><<<dim3(48, 6), 256, 0, stream>>>(Wih_d, WdTk, 32, nullptr, 0, W0dp, nullptr, nullptr, nullptr);
  gemm64<1><<<dim3(5, 48), 256, 0, stream>>>(CTpk, Wih_e, 32, nullptr, 0, nullptr, CTe, nullptr, nullptr);
  gemm64<1><<<dim3(5, 48), 256, 0, stream>>>(CTpk, Wih_d, 32, nullptr, 0, nullptr, CTd, nullptr, nullptr);
  build_cb<<<6144, 256, 0, stream>>>(CTe, enc_bih, weekday, CBe);
  build_cb<<<6144, 256, 0, stream>>>(CTd, dec_bih, weekday, CBd);

  // ---- encoder layer-0 gx (embed folded)
  gemm_gx0_enc<<<dim3(92, 24), 256, 0, stream>>>(Ap, W0ep, CTe, CBe, timev, GXbuf);

  // ---- zero initial hidden states
  hipMemsetAsync(Hf0[0], 0, (size_t)512 * 1024 * 4, stream);
  hipMemsetAsync(Hf1[0], 0, (size_t)512 * 1024 * 4, stream);
  hipMemsetAsync(Hp0[0], 0, (size_t)512 * 1024 * 2, stream);
  hipMemsetAsync(Hp1[0], 0, (size_t)512 * 1024 * 2, stream);

  // ---- 3-stage diagonal encoder (1536 uniform blocks, XCD-swizzled)
  int p0 = 0, p1 = 0;
  for (int k = 0; k <= TM1 + 1; ++k) {
    enc_diag<<<1536, 256, 0, stream>>>(k,
        Hp0[p0], Hf0[p0], Hf0[1 - p0], Hp0[1 - p0], Whh_e, enc_bhh, GXbuf, Xp,
        Wih_e + WLAYER, enc_bih + 3072, GX1p,
        Hp1[p1], Hf1[p1], Hf1[1 - p1], Hp1[1 - p1],
        Whh_e + WLAYER, enc_bhh + 3072);
    if (k < TM1) p0 ^= 1;
    if (k >= 2)  p1 ^= 1;
  }

  // ---- decoder (512-block cells, XCD-swizzled)
  for (int s = 0; s < HORIZON_; ++s) {
    dec_cell0<<<512, 256, 0, stream>>>(
        DCp, Hp0[p0], Hf0[p0], W0dp, Whh_d, dec_bhh, CTd, CBd, timev, s,
        Hf0[1 - p0], Hp0[1 - p0]);
    p0 ^= 1;
    gru_cell32<<<512, 256, 0, stream>>>(
        Hp0[p0], Hp1[p1], Hf1[p1],
        Wih_d + WLAYER, Whh_d + WLAYER, dec_bih + 3072, dec_bhh + 3072,
        Hf1[1 - p1], Hp1[1 - p1]);
    p1 ^= 1;
    gemm64<3><<<dim3(8, 6), 256, 0, stream>>>(
        Hp1[p1], WmT, 32, b_mlp, s, nullptr, DC, out, DCp);
  }
}